// Round 1
// baseline (8045.039 us; speedup 1.0000x reference)
//
#include <hip/hip_runtime.h>
#include <math.h>

// Problem dims
#define B_    256
#define P_    196
#define E_    2048
#define H_    2048
#define A_    512
#define EMB_  300
#define VIN_  262
#define VOUT_ 261
#define T_    7

// ---------------------------------------------------------------------------
// Generic fp32 GEMM:  C(M,N) = A(M,K; lda) @ B(N,K; ldb)^T  [+ bias | += ]
// 64x64 tile, BK=16, 256 threads, 4x4 per thread. LDS stored k-major so
// fragments read as 16B vector loads.
// ---------------------------------------------------------------------------
template<bool ACCUM>
__global__ __launch_bounds__(256)
void gemm_nt(const float* __restrict__ A, int lda,
             const float* __restrict__ Bm, int ldb,
             float* __restrict__ C, int ldc,
             const float* __restrict__ bias,
             int M, int N, int K)
{
    __shared__ float As[16][68];   // [k][row], pad 68 keeps 16B align + few conflicts
    __shared__ float Bs[16][68];
    const int tid  = threadIdx.x;
    const int tx   = tid & 15;     // N dir
    const int ty   = tid >> 4;     // M dir
    const int row0 = blockIdx.y * 64;
    const int col0 = blockIdx.x * 64;
    const int srow = tid >> 2;         // 0..63
    const int sk   = (tid & 3) << 2;   // 0,4,8,12

    float acc[4][4] = {};

    for (int k0 = 0; k0 < K; k0 += 16) {
        float4 av = make_float4(0.f,0.f,0.f,0.f);
        float4 bv = make_float4(0.f,0.f,0.f,0.f);
        const int kk0 = k0 + sk;
        const int ar  = row0 + srow;
        if (ar < M) {
            if (kk0 + 4 <= K) {
                av = *(const float4*)(A + (size_t)ar * lda + kk0);
            } else {
                float t0=0.f,t1=0.f,t2=0.f,t3=0.f;
                if (kk0+0 < K) t0 = A[(size_t)ar*lda + kk0+0];
                if (kk0+1 < K) t1 = A[(size_t)ar*lda + kk0+1];
                if (kk0+2 < K) t2 = A[(size_t)ar*lda + kk0+2];
                if (kk0+3 < K) t3 = A[(size_t)ar*lda + kk0+3];
                av = make_float4(t0,t1,t2,t3);
            }
        }
        const int br = col0 + srow;
        if (br < N) {
            if (kk0 + 4 <= K) {
                bv = *(const float4*)(Bm + (size_t)br * ldb + kk0);
            } else {
                float t0=0.f,t1=0.f,t2=0.f,t3=0.f;
                if (kk0+0 < K) t0 = Bm[(size_t)br*ldb + kk0+0];
                if (kk0+1 < K) t1 = Bm[(size_t)br*ldb + kk0+1];
                if (kk0+2 < K) t2 = Bm[(size_t)br*ldb + kk0+2];
                if (kk0+3 < K) t3 = Bm[(size_t)br*ldb + kk0+3];
                bv = make_float4(t0,t1,t2,t3);
            }
        }
        __syncthreads();   // protect previous iteration's reads
        As[sk+0][srow] = av.x; As[sk+1][srow] = av.y;
        As[sk+2][srow] = av.z; As[sk+3][srow] = av.w;
        Bs[sk+0][srow] = bv.x; Bs[sk+1][srow] = bv.y;
        Bs[sk+2][srow] = bv.z; Bs[sk+3][srow] = bv.w;
        __syncthreads();

        #pragma unroll
        for (int kk = 0; kk < 16; ++kk) {
            float4 a4 = *(const float4*)&As[kk][ty << 2];
            float4 b4 = *(const float4*)&Bs[kk][tx << 2];
            float aa[4] = {a4.x, a4.y, a4.z, a4.w};
            float bb[4] = {b4.x, b4.y, b4.z, b4.w};
            #pragma unroll
            for (int i = 0; i < 4; ++i)
                #pragma unroll
                for (int j = 0; j < 4; ++j)
                    acc[i][j] = fmaf(aa[i], bb[j], acc[i][j]);
        }
    }

    #pragma unroll
    for (int i = 0; i < 4; ++i) {
        const int r = row0 + (ty << 2) + i;
        if (r >= M) continue;
        #pragma unroll
        for (int j = 0; j < 4; ++j) {
            const int c = col0 + (tx << 2) + j;
            if (c >= N) continue;
            if (ACCUM) C[(size_t)r*ldc + c] += acc[i][j];
            else       C[(size_t)r*ldc + c]  = acc[i][j] + bias[c];
        }
    }
}

// ---------------------------------------------------------------------------
// e[b,p] = sum_a relu(att1[b,p,a] + att2[b,a]) * fw[a] + fb
// one wave per (b,p) row; 4 rows per block
// ---------------------------------------------------------------------------
__global__ __launch_bounds__(256)
void e_kernel(const float* __restrict__ att1, const float* __restrict__ att2,
              const float* __restrict__ fw, const float* __restrict__ fb,
              float* __restrict__ e)
{
    const int wid  = threadIdx.x >> 6;
    const int lane = threadIdx.x & 63;
    const int row  = blockIdx.x * 4 + wid;     // row < B_*P_ always (exact)
    const int b    = row / P_;
    const float* a1 = att1 + (size_t)row * A_;
    const float* a2 = att2 + (size_t)b * A_;
    float acc = 0.f;
    #pragma unroll
    for (int a = lane; a < A_; a += 64) {
        float v = a1[a] + a2[a];
        v = v > 0.f ? v : 0.f;
        acc = fmaf(v, fw[a], acc);
    }
    #pragma unroll
    for (int off = 32; off > 0; off >>= 1)
        acc += __shfl_down(acc, off);
    if (lane == 0) e[row] = acc + fb[0];
}

// ---------------------------------------------------------------------------
// softmax over P per batch; writes alpha scratch AND final output slice
// ---------------------------------------------------------------------------
__global__ __launch_bounds__(256)
void softmax_kernel(const float* __restrict__ e, float* __restrict__ alpha,
                    float* __restrict__ out_alpha /* d_out alphas base */, int t)
{
    const int b   = blockIdx.x;
    const int tid = threadIdx.x;
    const int wid = tid >> 6, lane = tid & 63;
    __shared__ float red[4];

    float v = (tid < P_) ? e[b * P_ + tid] : -1e30f;

    float m = v;
    #pragma unroll
    for (int off = 32; off > 0; off >>= 1)
        m = fmaxf(m, __shfl_xor(m, off));
    if (lane == 0) red[wid] = m;
    __syncthreads();
    m = fmaxf(fmaxf(red[0], red[1]), fmaxf(red[2], red[3]));
    __syncthreads();

    float p = (tid < P_) ? expf(v - m) : 0.f;
    float s = p;
    #pragma unroll
    for (int off = 32; off > 0; off >>= 1)
        s += __shfl_xor(s, off);
    if (lane == 0) red[wid] = s;
    __syncthreads();
    s = red[0] + red[1] + red[2] + red[3];

    if (tid < P_) {
        const float a = p / s;
        alpha[b * P_ + tid] = a;
        out_alpha[((size_t)b * T_ + t) * P_ + tid] = a;
    }
}

// ---------------------------------------------------------------------------
// awe[b,e] = sigmoid(gatelin[b,e]) * sum_p alpha[b,p] * enc[b,p,e]
// grid (E/256, B)
// ---------------------------------------------------------------------------
__global__ __launch_bounds__(256)
void awe_kernel(const float* __restrict__ alpha, const float* __restrict__ enc,
                const float* __restrict__ gatelin, float* __restrict__ awe)
{
    const int b  = blockIdx.y;
    const int ei = blockIdx.x * 256 + threadIdx.x;
    __shared__ float al[P_];
    if (threadIdx.x < P_) al[threadIdx.x] = alpha[b * P_ + threadIdx.x];
    __syncthreads();

    const float* ep = enc + (size_t)b * P_ * E_ + ei;
    float acc = 0.f;
    #pragma unroll 4
    for (int p = 0; p < P_; ++p)
        acc = fmaf(al[p], ep[(size_t)p * E_], acc);

    const float g  = gatelin[(size_t)b * E_ + ei];
    const float sg = 1.f / (1.f + expf(-g));
    awe[(size_t)b * E_ + ei] = sg * acc;
}

// ---------------------------------------------------------------------------
// LSTM cell elementwise update (in-place h, c) from gates (B,4H)
// ---------------------------------------------------------------------------
__global__ __launch_bounds__(256)
void lstm_kernel(const float* __restrict__ gates, float* __restrict__ c,
                 float* __restrict__ h)
{
    const int idx = blockIdx.x * 256 + threadIdx.x;  // b*H + j
    const int b = idx >> 11;
    const int j = idx & (H_ - 1);
    const float* g = gates + (size_t)b * 4 * H_;
    const float gi = g[j];
    const float gf = g[H_ + j];
    const float gg = g[2 * H_ + j];
    const float go = g[3 * H_ + j];
    const float si = 1.f / (1.f + expf(-gi));
    const float sf = 1.f / (1.f + expf(-gf));
    const float so = 1.f / (1.f + expf(-go));
    const float cn = sf * c[idx] + si * tanhf(gg);
    c[idx] = cn;
    h[idx] = so * tanhf(cn);
}

// ---------------------------------------------------------------------------
// gather embedding rows for step t: xemb[b,:] = emb_W[ann[b*T+t], :]
// ---------------------------------------------------------------------------
__global__ __launch_bounds__(256)
void gather_kernel(const int* __restrict__ ann, const float* __restrict__ embW,
                   float* __restrict__ xemb, int t)
{
    const int b = blockIdx.x;
    const int r = ann[b * T_ + t];
    for (int j = threadIdx.x; j < EMB_; j += 256)
        xemb[(size_t)b * EMB_ + j] = embW[(size_t)r * EMB_ + j];
}

__global__ __launch_bounds__(256)
void addvec_kernel(const float* __restrict__ a, const float* __restrict__ b,
                   float* __restrict__ o, int n)
{
    const int i = blockIdx.x * 256 + threadIdx.x;
    if (i < n) o[i] = a[i] + b[i];
}

// ---------------------------------------------------------------------------
extern "C" void kernel_launch(void* const* d_in, const int* in_sizes, int n_in,
                              void* d_out, int out_size, void* d_ws, size_t ws_size,
                              hipStream_t stream)
{
    const float* enc      = (const float*)d_in[0];   // (B,P,E)
    const float* enc_out  = (const float*)d_in[1];   // (B,E)
    const int*   ann      = (const int*)  d_in[2];   // (B,T)
    const float* emb_W    = (const float*)d_in[4];   // (VIN,EMB)
    const float* feat_W   = (const float*)d_in[5];   // (H,E)
    const float* feat_b   = (const float*)d_in[6];
    const float* W_ih     = (const float*)d_in[7];   // (4H, EMB+E)
    const float* W_hh     = (const float*)d_in[8];   // (4H, H)
    const float* b_ih     = (const float*)d_in[9];
    const float* b_hh     = (const float*)d_in[10];
    const float* enc_attW = (const float*)d_in[11];  // (A,E)
    const float* enc_attb = (const float*)d_in[12];
    const float* dec_attW = (const float*)d_in[13];  // (A,H)
    const float* dec_attb = (const float*)d_in[14];
    const float* full_attW= (const float*)d_in[15];  // (1,A)
    const float* full_attb= (const float*)d_in[16];
    const float* fbeta_W  = (const float*)d_in[17];  // (E,H)
    const float* fbeta_b  = (const float*)d_in[18];
    const float* fc_W     = (const float*)d_in[19];  // (VOUT,H)
    const float* fc_b     = (const float*)d_in[20];

    float* out   = (float*)d_out;
    float* out_y = out;                                 // (B,T,VOUT)
    float* out_a = out + (size_t)B_ * T_ * VOUT_;       // (B,T,P)

    // workspace layout (floats)
    float* ws = (float*)d_ws;
    size_t off = 0;
    float* att1    = ws + off; off += (size_t)B_ * P_ * A_;   // 25.69M
    float* hbuf    = ws + off; off += (size_t)B_ * H_;
    float* cbuf    = ws + off; off += (size_t)B_ * H_;
    float* att2    = ws + off; off += (size_t)B_ * A_;
    float* ebuf    = ws + off; off += (size_t)B_ * P_;
    float* alpha   = ws + off; off += (size_t)B_ * P_;
    float* gatelin = ws + off; off += (size_t)B_ * E_;
    float* awe     = ws + off; off += (size_t)B_ * E_;
    float* gates   = ws + off; off += (size_t)B_ * 4 * H_;
    float* xemb    = ws + off; off += (size_t)B_ * EMB_;
    float* bias4h  = ws + off; off += (size_t)4 * H_;
    (void)ws_size; (void)n_in; (void)in_sizes; (void)out_size;

    const dim3 blk(256);

    // combined LSTM bias
    addvec_kernel<<<dim3((4 * H_ + 255) / 256), blk, 0, stream>>>(b_ih, b_hh, bias4h, 4 * H_);

    // att1 = enc @ enc_att_W^T + b : M=B*P, N=A, K=E
    {
        dim3 g((A_ + 63) / 64, (B_ * P_ + 63) / 64);
        gemm_nt<false><<<g, blk, 0, stream>>>(enc, E_, enc_attW, E_, att1, A_,
                                              enc_attb, B_ * P_, A_, E_);
    }
    // h0 = enc_out @ feat_W^T + b : M=B, N=H, K=E
    {
        dim3 g((H_ + 63) / 64, (B_ + 63) / 64);
        gemm_nt<false><<<g, blk, 0, stream>>>(enc_out, E_, feat_W, E_, hbuf, H_,
                                              feat_b, B_, H_, E_);
    }
    // c0 = 0
    hipMemsetAsync(cbuf, 0, (size_t)B_ * H_ * sizeof(float), stream);

    for (int t = 0; t < T_; ++t) {
        // att2 = h @ dec_att_W^T + b : (B,A)
        {
            dim3 g((A_ + 63) / 64, (B_ + 63) / 64);
            gemm_nt<false><<<g, blk, 0, stream>>>(hbuf, H_, dec_attW, H_, att2, A_,
                                                  dec_attb, B_, A_, H_);
        }
        // e, softmax
        e_kernel<<<dim3(B_ * P_ / 4), blk, 0, stream>>>(att1, att2, full_attW, full_attb, ebuf);
        softmax_kernel<<<dim3(B_), blk, 0, stream>>>(ebuf, alpha, out_a, t);

        // gate pre-activation: gatelin = h @ fbeta_W^T + b : (B,E)
        {
            dim3 g((E_ + 63) / 64, (B_ + 63) / 64);
            gemm_nt<false><<<g, blk, 0, stream>>>(hbuf, H_, fbeta_W, H_, gatelin, E_,
                                                  fbeta_b, B_, E_, H_);
        }
        // awe = sigmoid(gatelin) * (alpha @ enc)
        awe_kernel<<<dim3(E_ / 256, B_), blk, 0, stream>>>(alpha, enc, gatelin, awe);

        // x-embedding gather
        gather_kernel<<<dim3(B_), blk, 0, stream>>>(ann, emb_W, xemb, t);

        // gates = xemb @ W_ih[:, :EMB]^T + (b_ih+b_hh)
        {
            dim3 g((4 * H_ + 63) / 64, (B_ + 63) / 64);
            gemm_nt<false><<<g, blk, 0, stream>>>(xemb, EMB_, W_ih, EMB_ + E_, gates, 4 * H_,
                                                  bias4h, B_, 4 * H_, EMB_);
        }
        // gates += awe @ W_ih[:, EMB:]^T
        {
            dim3 g((4 * H_ + 63) / 64, (B_ + 63) / 64);
            gemm_nt<true><<<g, blk, 0, stream>>>(awe, E_, W_ih + EMB_, EMB_ + E_, gates, 4 * H_,
                                                 nullptr, B_, 4 * H_, E_);
        }
        // gates += h @ W_hh^T
        {
            dim3 g((4 * H_ + 63) / 64, (B_ + 63) / 64);
            gemm_nt<true><<<g, blk, 0, stream>>>(hbuf, H_, W_hh, H_, gates, 4 * H_,
                                                 nullptr, B_, 4 * H_, H_);
        }
        // LSTM cell
        lstm_kernel<<<dim3(B_ * H_ / 256), blk, 0, stream>>>(gates, cbuf, hbuf);

        // yhat = h @ fc_W^T + b -> out[:, t, :]  (ldc = T*VOUT)
        {
            dim3 g((VOUT_ + 63) / 64, (B_ + 63) / 64);
            gemm_nt<false><<<g, blk, 0, stream>>>(hbuf, H_, fc_W, H_, out_y + (size_t)t * VOUT_,
                                                  T_ * VOUT_, fc_b, B_, VOUT_, H_);
        }
    }
}

// Round 2
// 3271.460 us; speedup vs baseline: 2.4592x; 2.4592x over previous
//
#include <hip/hip_runtime.h>
#include <math.h>

// Problem dims
#define B_    256
#define P_    196
#define E_    2048
#define H_    2048
#define A_    512
#define EMB_  300
#define VIN_  262
#define VOUT_ 261
#define T_    7
#define KCAT_ 4416   // EMB_ + E_ + H_ (=4396) padded to multiple of 32

typedef __attribute__((ext_vector_type(8))) short          short8_t;
typedef __attribute__((ext_vector_type(8))) unsigned short ushort8_t;
typedef __attribute__((ext_vector_type(4))) float          f32x4;

__device__ __forceinline__ unsigned short f2b(float f) {
    union { float f; unsigned int u; } v; v.f = f;
    unsigned int x = v.u;
    unsigned int r = (x + 0x7fffu + ((x >> 16) & 1u)) >> 16;   // RNE
    return (unsigned short)r;
}
__device__ __forceinline__ float b2f(unsigned short u) {
    union { unsigned int u; float f; } v; v.u = ((unsigned int)u) << 16;
    return v.f;
}

// ---------------------------------------------------------------------------
// MFMA GEMM:  C(M,N) = A(M,K) @ B(N,K)^T + bias
//   A: fp32 (converted on the fly) or bf16 (ABF16)
//   C: fp32 or bf16 (C16)
//   B: bf16 (pre-converted weights)
// Tile 64(M) x 128(N) x 32(K); 4 waves as 2x2; wave tile 32x64 (2x4 frags of
// 16x16x32). LDS rows padded to 40 elems to spread banks.
// ---------------------------------------------------------------------------
template<bool ABF16, bool C16>
__global__ __launch_bounds__(256)
void gemm_mfma(const void* __restrict__ Ap, int lda,
               const unsigned short* __restrict__ Bw, int ldb,
               void* __restrict__ Cp, int ldc,
               const float* __restrict__ bias,
               int M, int N, int K)
{
    __shared__ __align__(16) unsigned short As[64][40];
    __shared__ __align__(16) unsigned short Bs[128][40];

    const int tid  = threadIdx.x;
    const int lane = tid & 63;
    const int wid  = tid >> 6;
    const int wr   = wid >> 1;          // 0..1 (M dir)
    const int wc   = wid & 1;           // 0..1 (N dir)
    const int row0 = blockIdx.y * 64;
    const int col0 = blockIdx.x * 128;

    // A staging coords: 64 rows x 4 segs of 8
    const int ar = tid >> 2;
    const int as = (tid & 3) * 8;
    // B staging coords: 128 rows x 2 halves of 16
    const int br = tid >> 1;
    const int bs = (tid & 1) * 16;

    const int lr = lane & 15;
    const int lk = (lane >> 4) * 8;

    f32x4 acc[2][4];
    #pragma unroll
    for (int m = 0; m < 2; ++m)
        #pragma unroll
        for (int n = 0; n < 4; ++n)
            acc[m][n] = (f32x4){0.f, 0.f, 0.f, 0.f};

    for (int k0 = 0; k0 < K; k0 += 32) {
        // ---- load to regs
        ushort8_t aval = {0,0,0,0,0,0,0,0};
        if (row0 + ar < M) {
            if (ABF16) {
                const unsigned short* A16 = (const unsigned short*)Ap;
                aval = *(const ushort8_t*)(A16 + (size_t)(row0 + ar) * lda + k0 + as);
            } else {
                const float* Af = (const float*)Ap;
                const float* p = Af + (size_t)(row0 + ar) * lda + k0 + as;
                float4 v0 = *(const float4*)(p);
                float4 v1 = *(const float4*)(p + 4);
                aval[0] = f2b(v0.x); aval[1] = f2b(v0.y);
                aval[2] = f2b(v0.z); aval[3] = f2b(v0.w);
                aval[4] = f2b(v1.x); aval[5] = f2b(v1.y);
                aval[6] = f2b(v1.z); aval[7] = f2b(v1.w);
            }
        }
        ushort8_t bv0 = {0,0,0,0,0,0,0,0}, bv1 = {0,0,0,0,0,0,0,0};
        if (col0 + br < N) {
            const unsigned short* p = Bw + (size_t)(col0 + br) * ldb + k0 + bs;
            bv0 = *(const ushort8_t*)(p);
            bv1 = *(const ushort8_t*)(p + 8);
        }
        __syncthreads();   // protect previous iteration's LDS reads
        *(ushort8_t*)&As[ar][as]     = aval;
        *(ushort8_t*)&Bs[br][bs]     = bv0;
        *(ushort8_t*)&Bs[br][bs + 8] = bv1;
        __syncthreads();

        // ---- fragments + MFMA
        short8_t af[2], bf[4];
        #pragma unroll
        for (int m = 0; m < 2; ++m)
            af[m] = *(const short8_t*)&As[wr * 32 + m * 16 + lr][lk];
        #pragma unroll
        for (int n = 0; n < 4; ++n)
            bf[n] = *(const short8_t*)&Bs[wc * 64 + n * 16 + lr][lk];
        #pragma unroll
        for (int m = 0; m < 2; ++m)
            #pragma unroll
            for (int n = 0; n < 4; ++n)
                acc[m][n] = __builtin_amdgcn_mfma_f32_16x16x32_bf16(
                    af[m], bf[n], acc[m][n], 0, 0, 0);
    }

    // ---- epilogue: D col = lane&15, row = (lane>>4)*4 + reg
    #pragma unroll
    for (int m = 0; m < 2; ++m) {
        const int grow0 = row0 + wr * 32 + m * 16 + (lane >> 4) * 4;
        #pragma unroll
        for (int n = 0; n < 4; ++n) {
            const int gcol = col0 + wc * 64 + n * 16 + lr;
            if (gcol >= N) continue;
            const float bv = bias[gcol];
            #pragma unroll
            for (int r = 0; r < 4; ++r) {
                const int grow = grow0 + r;
                if (grow >= M) continue;
                const float val = acc[m][n][r] + bv;
                if (C16) ((unsigned short*)Cp)[(size_t)grow * ldc + gcol] = f2b(val);
                else     ((float*)Cp)[(size_t)grow * ldc + gcol] = val;
            }
        }
    }
}

// ---------------------------------------------------------------------------
// fp32 -> bf16 conversion, 8 elems/thread (n must be multiple of 8)
// ---------------------------------------------------------------------------
__global__ __launch_bounds__(256)
void cvt_bf16_kernel(const float* __restrict__ in, unsigned short* __restrict__ out,
                     int n8)
{
    const int idx = blockIdx.x * 256 + threadIdx.x;
    if (idx >= n8) return;
    const size_t base = (size_t)idx * 8;
    float4 v0 = *(const float4*)(in + base);
    float4 v1 = *(const float4*)(in + base + 4);
    ushort8_t u;
    u[0]=f2b(v0.x); u[1]=f2b(v0.y); u[2]=f2b(v0.z); u[3]=f2b(v0.w);
    u[4]=f2b(v1.x); u[5]=f2b(v1.y); u[6]=f2b(v1.z); u[7]=f2b(v1.w);
    *(ushort8_t*)(out + base) = u;
}

// ---------------------------------------------------------------------------
// build wcat bf16 (8192 x 4416): [W_ih (2348) | W_hh (2048) | pad 20]
// grid (5, 8192): thread handles 4 consecutive k
// ---------------------------------------------------------------------------
__global__ __launch_bounds__(256)
void build_wcat_kernel(const float* __restrict__ W_ih, const float* __restrict__ W_hh,
                       unsigned short* __restrict__ wcat)
{
    const int row = blockIdx.y;
    const int k0  = (blockIdx.x * 256 + threadIdx.x) * 4;
    if (k0 >= KCAT_) return;
    unsigned short u[4];
    #pragma unroll
    for (int i = 0; i < 4; ++i) {
        const int k = k0 + i;
        float v = 0.f;
        if (k < EMB_ + E_)            v = W_ih[(size_t)row * (EMB_ + E_) + k];
        else if (k < EMB_ + E_ + H_)  v = W_hh[(size_t)row * H_ + (k - EMB_ - E_)];
        u[i] = f2b(v);
    }
    *(ushort8_t*)0; // (unused; silence nothing)
    unsigned short* p = wcat + (size_t)row * KCAT_ + k0;
    p[0]=u[0]; p[1]=u[1]; p[2]=u[2]; p[3]=u[3];
}

// ---------------------------------------------------------------------------
// e[b,p] = sum_a relu(att1_bf16[b,p,a] + att2[b,a]) * fw[a] + fb
// ---------------------------------------------------------------------------
__global__ __launch_bounds__(256)
void e_kernel(const unsigned short* __restrict__ att1, const float* __restrict__ att2,
              const float* __restrict__ fw, const float* __restrict__ fb,
              float* __restrict__ e)
{
    const int wid  = threadIdx.x >> 6;
    const int lane = threadIdx.x & 63;
    const int row  = blockIdx.x * 4 + wid;
    const int b    = row / P_;
    const unsigned short* a1 = att1 + (size_t)row * A_;
    const float* a2 = att2 + (size_t)b * A_;
    float acc = 0.f;
    #pragma unroll
    for (int a = lane; a < A_; a += 64) {
        float v = b2f(a1[a]) + a2[a];
        v = v > 0.f ? v : 0.f;
        acc = fmaf(v, fw[a], acc);
    }
    #pragma unroll
    for (int off = 32; off > 0; off >>= 1)
        acc += __shfl_down(acc, off);
    if (lane == 0) e[row] = acc + fb[0];
}

// ---------------------------------------------------------------------------
__global__ __launch_bounds__(256)
void softmax_kernel(const float* __restrict__ e, float* __restrict__ alpha,
                    float* __restrict__ out_alpha, int t)
{
    const int b   = blockIdx.x;
    const int tid = threadIdx.x;
    const int wid = tid >> 6, lane = tid & 63;
    __shared__ float red[4];

    float v = (tid < P_) ? e[b * P_ + tid] : -1e30f;

    float m = v;
    #pragma unroll
    for (int off = 32; off > 0; off >>= 1)
        m = fmaxf(m, __shfl_xor(m, off));
    if (lane == 0) red[wid] = m;
    __syncthreads();
    m = fmaxf(fmaxf(red[0], red[1]), fmaxf(red[2], red[3]));
    __syncthreads();

    float p = (tid < P_) ? expf(v - m) : 0.f;
    float s = p;
    #pragma unroll
    for (int off = 32; off > 0; off >>= 1)
        s += __shfl_xor(s, off);
    if (lane == 0) red[wid] = s;
    __syncthreads();
    s = red[0] + red[1] + red[2] + red[3];

    if (tid < P_) {
        const float a = p / s;
        alpha[b * P_ + tid] = a;
        out_alpha[((size_t)b * T_ + t) * P_ + tid] = a;
    }
}

// ---------------------------------------------------------------------------
// xcat[b, EMB_+ei] = sigmoid(gatelin[b,ei]) * sum_p alpha[b,p]*enc[b,p,ei]
// ---------------------------------------------------------------------------
__global__ __launch_bounds__(256)
void awe_kernel(const float* __restrict__ alpha,
                const float* __restrict__ encf, const unsigned short* __restrict__ enc16,
                int use16,
                const float* __restrict__ gatelin, float* __restrict__ xcat)
{
    const int b  = blockIdx.y;
    const int ei = blockIdx.x * 256 + threadIdx.x;
    __shared__ float al[P_];
    if (threadIdx.x < P_) al[threadIdx.x] = alpha[b * P_ + threadIdx.x];
    __syncthreads();

    float acc = 0.f;
    if (use16) {
        const unsigned short* ep = enc16 + (size_t)b * P_ * E_ + ei;
        #pragma unroll 4
        for (int p = 0; p < P_; ++p)
            acc = fmaf(al[p], b2f(ep[(size_t)p * E_]), acc);
    } else {
        const float* ep = encf + (size_t)b * P_ * E_ + ei;
        #pragma unroll 4
        for (int p = 0; p < P_; ++p)
            acc = fmaf(al[p], ep[(size_t)p * E_], acc);
    }

    const float g  = gatelin[(size_t)b * E_ + ei];
    const float sg = 1.f / (1.f + expf(-g));
    xcat[(size_t)b * KCAT_ + EMB_ + ei] = sg * acc;
}

// ---------------------------------------------------------------------------
__global__ __launch_bounds__(256)
void lstm_kernel(const float* __restrict__ gates, float* __restrict__ c,
                 float* __restrict__ h)
{
    const int idx = blockIdx.x * 256 + threadIdx.x;  // b*H + j
    const int b = idx >> 11;
    const int j = idx & (H_ - 1);
    const float* g = gates + (size_t)b * 4 * H_;
    const float gi = g[j];
    const float gf = g[H_ + j];
    const float gg = g[2 * H_ + j];
    const float go = g[3 * H_ + j];
    const float si = 1.f / (1.f + expf(-gi));
    const float sf = 1.f / (1.f + expf(-gf));
    const float so = 1.f / (1.f + expf(-go));
    const float cn = sf * c[idx] + si * tanhf(gg);
    c[idx] = cn;
    h[idx] = so * tanhf(cn);
}

// ---------------------------------------------------------------------------
__global__ __launch_bounds__(256)
void gather_kernel(const int* __restrict__ ann, const float* __restrict__ embW,
                   float* __restrict__ xcat, int t)
{
    const int b = blockIdx.x;
    const int r = ann[b * T_ + t];
    for (int j = threadIdx.x; j < EMB_; j += 256)
        xcat[(size_t)b * KCAT_ + j] = embW[(size_t)r * EMB_ + j];
}

__global__ __launch_bounds__(256)
void copyh_kernel(const float* __restrict__ h, float* __restrict__ xcat)
{
    const int idx = blockIdx.x * 256 + threadIdx.x;  // b*H + j
    const int b = idx >> 11;
    const int j = idx & (H_ - 1);
    xcat[(size_t)b * KCAT_ + EMB_ + E_ + j] = h[idx];
}

__global__ __launch_bounds__(256)
void addvec_kernel(const float* __restrict__ a, const float* __restrict__ b,
                   float* __restrict__ o, int n)
{
    const int i = blockIdx.x * 256 + threadIdx.x;
    if (i < n) o[i] = a[i] + b[i];
}

// ---------------------------------------------------------------------------
extern "C" void kernel_launch(void* const* d_in, const int* in_sizes, int n_in,
                              void* d_out, int out_size, void* d_ws, size_t ws_size,
                              hipStream_t stream)
{
    const float* enc      = (const float*)d_in[0];   // (B,P,E)
    const float* enc_out  = (const float*)d_in[1];   // (B,E)
    const int*   ann      = (const int*)  d_in[2];   // (B,T)
    const float* emb_W    = (const float*)d_in[4];   // (VIN,EMB)
    const float* feat_W   = (const float*)d_in[5];   // (H,E)
    const float* feat_b   = (const float*)d_in[6];
    const float* W_ih     = (const float*)d_in[7];   // (4H, EMB+E)
    const float* W_hh     = (const float*)d_in[8];   // (4H, H)
    const float* b_ih     = (const float*)d_in[9];
    const float* b_hh     = (const float*)d_in[10];
    const float* enc_attW = (const float*)d_in[11];  // (A,E)
    const float* enc_attb = (const float*)d_in[12];
    const float* dec_attW = (const float*)d_in[13];  // (A,H)
    const float* dec_attb = (const float*)d_in[14];
    const float* full_attW= (const float*)d_in[15];  // (1,A)
    const float* full_attb= (const float*)d_in[16];
    const float* fbeta_W  = (const float*)d_in[17];  // (E,H)
    const float* fbeta_b  = (const float*)d_in[18];
    const float* fc_W     = (const float*)d_in[19];  // (VOUT,H)
    const float* fc_b     = (const float*)d_in[20];
    (void)in_sizes; (void)n_in; (void)out_size;

    float* out   = (float*)d_out;
    float* out_y = out;                                 // (B,T,VOUT)
    float* out_a = out + (size_t)B_ * T_ * VOUT_;       // (B,T,P)

    // ---- workspace layout (256B aligned chunks)
    char* base = (char*)d_ws;
    size_t off = 0;
    auto alloc = [&](size_t bytes) -> char* {
        char* p = base + off;
        off += (bytes + 255) & ~(size_t)255;
        return p;
    };
    unsigned short* att1_16  = (unsigned short*)alloc((size_t)B_ * P_ * A_ * 2);
    unsigned short* wcat16   = (unsigned short*)alloc((size_t)4 * H_ * KCAT_ * 2);
    unsigned short* encattW16= (unsigned short*)alloc((size_t)A_ * E_ * 2);
    unsigned short* featW16  = (unsigned short*)alloc((size_t)H_ * E_ * 2);
    unsigned short* decattW16= (unsigned short*)alloc((size_t)A_ * H_ * 2);
    unsigned short* fbetaW16 = (unsigned short*)alloc((size_t)E_ * H_ * 2);
    unsigned short* fcW16    = (unsigned short*)alloc((size_t)VOUT_ * H_ * 2);
    float* xcat    = (float*)alloc((size_t)B_ * KCAT_ * 4);
    float* hbuf    = (float*)alloc((size_t)B_ * H_ * 4);
    float* cbuf    = (float*)alloc((size_t)B_ * H_ * 4);
    float* att2    = (float*)alloc((size_t)B_ * A_ * 4);
    float* ebuf    = (float*)alloc((size_t)B_ * P_ * 4);
    float* alpha   = (float*)alloc((size_t)B_ * P_ * 4);
    float* gatelin = (float*)alloc((size_t)B_ * E_ * 4);
    float* gates   = (float*)alloc((size_t)B_ * 4 * H_ * 4);
    float* bias4h  = (float*)alloc((size_t)4 * H_ * 4);
    // optional bf16 enc (205.5 MB)
    const size_t enc_elems = (size_t)B_ * P_ * E_;
    const int use16 = (off + enc_elems * 2 <= ws_size) ? 1 : 0;
    unsigned short* enc16 = use16 ? (unsigned short*)alloc(enc_elems * 2) : nullptr;

    const dim3 blk(256);

    // ---- one-time conversions (every launch; deterministic)
    addvec_kernel<<<dim3((4 * H_ + 255) / 256), blk, 0, stream>>>(b_ih, b_hh, bias4h, 4 * H_);
    cvt_bf16_kernel<<<dim3((int)((A_ * E_ / 8 + 255) / 256)), blk, 0, stream>>>(enc_attW, encattW16, A_ * E_ / 8);
    cvt_bf16_kernel<<<dim3((int)((H_ * E_ / 8 + 255) / 256)), blk, 0, stream>>>(feat_W, featW16, H_ * E_ / 8);
    cvt_bf16_kernel<<<dim3((int)((A_ * H_ / 8 + 255) / 256)), blk, 0, stream>>>(dec_attW, decattW16, A_ * H_ / 8);
    cvt_bf16_kernel<<<dim3((int)((E_ * H_ / 8 + 255) / 256)), blk, 0, stream>>>(fbeta_W, fbetaW16, E_ * H_ / 8);
    cvt_bf16_kernel<<<dim3((int)((VOUT_ * H_ / 8 + 255) / 256)), blk, 0, stream>>>(fc_W, fcW16, VOUT_ * H_ / 8);
    build_wcat_kernel<<<dim3((KCAT_ / 4 + 255) / 256, 4 * H_), blk, 0, stream>>>(W_ih, W_hh, wcat16);
    if (use16) {
        const int n8 = (int)(enc_elems / 8);
        cvt_bf16_kernel<<<dim3((n8 + 255) / 256), blk, 0, stream>>>(enc, enc16, n8);
    }
    hipMemsetAsync(cbuf, 0, (size_t)B_ * H_ * sizeof(float), stream);
    hipMemsetAsync(xcat, 0, (size_t)B_ * KCAT_ * sizeof(float), stream);

    // ---- att1 = enc @ enc_att_W^T + b  ->  bf16 (B*P, A)
    {
        dim3 g((A_ + 127) / 128, (B_ * P_) / 64);
        if (use16)
            gemm_mfma<true, true><<<g, blk, 0, stream>>>(enc16, E_, encattW16, E_,
                att1_16, A_, enc_attb, B_ * P_, A_, E_);
        else
            gemm_mfma<false, true><<<g, blk, 0, stream>>>(enc, E_, encattW16, E_,
                att1_16, A_, enc_attb, B_ * P_, A_, E_);
    }
    // ---- h0 = enc_out @ feat_W^T + b
    {
        dim3 g((H_ + 127) / 128, B_ / 64);
        gemm_mfma<false, false><<<g, blk, 0, stream>>>(enc_out, E_, featW16, E_,
            hbuf, H_, feat_b, B_, H_, E_);
    }

    for (int t = 0; t < T_; ++t) {
        // att2 = h @ dec_att_W^T + b
        {
            dim3 g((A_ + 127) / 128, B_ / 64);
            gemm_mfma<false, false><<<g, blk, 0, stream>>>(hbuf, H_, decattW16, H_,
                att2, A_, dec_attb, B_, A_, H_);
        }
        e_kernel<<<dim3(B_ * P_ / 4), blk, 0, stream>>>(att1_16, att2, full_attW, full_attb, ebuf);
        softmax_kernel<<<dim3(B_), blk, 0, stream>>>(ebuf, alpha, out_a, t);

        // gatelin = h @ fbeta_W^T + b
        {
            dim3 g((E_ + 127) / 128, B_ / 64);
            gemm_mfma<false, false><<<g, blk, 0, stream>>>(hbuf, H_, fbetaW16, H_,
                gatelin, E_, fbeta_b, B_, E_, H_);
        }
        // awe -> xcat[:, EMB:EMB+E]
        awe_kernel<<<dim3(E_ / 256, B_), blk, 0, stream>>>(alpha, enc, enc16, use16,
                                                           gatelin, xcat);
        // emb -> xcat[:, :EMB] ; h -> xcat[:, EMB+E:]
        gather_kernel<<<dim3(B_), blk, 0, stream>>>(ann, emb_W, xcat, t);
        copyh_kernel<<<dim3(B_ * H_ / 256), blk, 0, stream>>>(hbuf, xcat);

        // gates = xcat @ wcat^T + (b_ih + b_hh)
        {
            dim3 g((4 * H_ + 127) / 128, B_ / 64);
            gemm_mfma<false, false><<<g, blk, 0, stream>>>(xcat, KCAT_, wcat16, KCAT_,
                gates, 4 * H_, bias4h, B_, 4 * H_, KCAT_);
        }
        lstm_kernel<<<dim3(B_ * H_ / 256), blk, 0, stream>>>(gates, cbuf, hbuf);

        // yhat = h @ fc_W^T + b -> out[:, t, :]
        {
            dim3 g((VOUT_ + 127) / 128, B_ / 64);
            gemm_mfma<false, false><<<g, blk, 0, stream>>>(hbuf, H_, fcW16, H_,
                out_y + (size_t)t * VOUT_, T_ * VOUT_, fc_b, B_, VOUT_, H_);
        }
    }
}

// Round 3
// 1361.936 us; speedup vs baseline: 5.9071x; 2.4021x over previous
//
#include <hip/hip_runtime.h>
#include <math.h>

// Problem dims
#define B_    256
#define P_    196
#define E_    2048
#define H_    2048
#define A_    512
#define EMB_  300
#define VOUT_ 261
#define T_    7

// xcat layout: [ h (2048) | emb (300) | awe (2048) | pad (84) ]  K = 4480
#define KPAD_   4480
#define EMBOFF_ 2048
#define AWEOFF_ 2348
#define KREAL_  4396

#define NSTEP_  2880   // combined step GEMM cols: att2 512 + fbeta 2048 + fc 320
#define FCN_    320

typedef __attribute__((ext_vector_type(8))) short          short8_t;
typedef __attribute__((ext_vector_type(8))) unsigned short ushort8_t;
typedef __attribute__((ext_vector_type(4))) float          f32x4;

__device__ __forceinline__ unsigned short f2b(float f) {
    union { float f; unsigned int u; } v; v.f = f;
    unsigned int x = v.u;
    unsigned int r = (x + 0x7fffu + ((x >> 16) & 1u)) >> 16;   // RNE
    return (unsigned short)r;
}
__device__ __forceinline__ float b2f(unsigned short u) {
    union { unsigned int u; float f; } v; v.u = ((unsigned int)u) << 16;
    return v.f;
}

// ---------------------------------------------------------------------------
// Skinny-M GEMM: Cpart[ksplit](256, N) = A(256, K)bf16 @ B(N, K)bf16^T
// BM=256 (weights streamed once), BN=64, K-step 64, reg-prefetch dbuf,
// XOR-swizzled LDS (16B slot ^ row&7) -> conflict-free ds_read_b128.
// grid = (N/64, KSPLIT); Kper = K/KSPLIT (multiple of 64).
// ---------------------------------------------------------------------------
__global__ __launch_bounds__(256)
void gemm_skinny(const unsigned short* __restrict__ Ab, int lda,
                 const unsigned short* __restrict__ Bw, int ldb,
                 float* __restrict__ Cpart, int N, int Kper)
{
    __shared__ ushort8_t As8[256 * 8];   // 32 KB, [row][slot]
    __shared__ ushort8_t Bs8[64 * 8];    //  8 KB

    const int tid  = threadIdx.x;
    const int lane = tid & 63;
    const int w    = tid >> 6;
    const int col0 = blockIdx.x * 64;
    const int kbase = blockIdx.y * Kper;
    float* __restrict__ Cs = Cpart + (size_t)blockIdx.y * 256 * N;

    const int rb  = tid >> 3;            // 0..31
    const int seg = tid & 7;
    const int swz = seg ^ (rb & 7);      // (row&7) invariant under +32

    const unsigned short* Ap = Ab + (size_t)rb * lda + kbase + seg * 8;
    const unsigned short* Bp = Bw + (size_t)(col0 + rb) * ldb + kbase + seg * 8;

    const int lr = lane & 15;
    const int hi = lane >> 4;

    f32x4 acc[4][4];
    #pragma unroll
    for (int m = 0; m < 4; ++m)
        #pragma unroll
        for (int n = 0; n < 4; ++n)
            acc[m][n] = (f32x4){0.f, 0.f, 0.f, 0.f};

    ushort8_t aR[8], bR[2];
    #pragma unroll
    for (int i = 0; i < 8; ++i)
        aR[i] = *(const ushort8_t*)(Ap + (size_t)i * 32 * lda);
    bR[0] = *(const ushort8_t*)(Bp);
    bR[1] = *(const ushort8_t*)(Bp + (size_t)32 * ldb);

    for (int k0 = 0; k0 < Kper; k0 += 64) {
        __syncthreads();                       // LDS consumers of prev step done
        #pragma unroll
        for (int i = 0; i < 8; ++i)
            As8[(rb + i * 32) * 8 + swz] = aR[i];
        Bs8[rb * 8 + swz]        = bR[0];
        Bs8[(rb + 32) * 8 + swz] = bR[1];
        __syncthreads();
        if (k0 + 64 < Kper) {                  // issue next-tile loads early
            #pragma unroll
            for (int i = 0; i < 8; ++i)
                aR[i] = *(const ushort8_t*)(Ap + (size_t)i * 32 * lda + k0 + 64);
            bR[0] = *(const ushort8_t*)(Bp + k0 + 64);
            bR[1] = *(const ushort8_t*)(Bp + (size_t)32 * ldb + k0 + 64);
        }
        #pragma unroll
        for (int kc = 0; kc < 2; ++kc) {
            short8_t af[4], bf[4];
            #pragma unroll
            for (int m = 0; m < 4; ++m) {
                const int row = w * 64 + m * 16 + lr;
                af[m] = *(const short8_t*)&As8[row * 8 + ((kc * 4 + hi) ^ (row & 7))];
            }
            #pragma unroll
            for (int n = 0; n < 4; ++n) {
                const int row = n * 16 + lr;
                bf[n] = *(const short8_t*)&Bs8[row * 8 + ((kc * 4 + hi) ^ (row & 7))];
            }
            #pragma unroll
            for (int m = 0; m < 4; ++m)
                #pragma unroll
                for (int n = 0; n < 4; ++n)
                    acc[m][n] = __builtin_amdgcn_mfma_f32_16x16x32_bf16(
                        af[m], bf[n], acc[m][n], 0, 0, 0);
        }
    }

    // C/D: col = lane&15, row = (lane>>4)*4 + reg
    #pragma unroll
    for (int m = 0; m < 4; ++m) {
        const int grow0 = w * 64 + m * 16 + hi * 4;
        #pragma unroll
        for (int n = 0; n < 4; ++n) {
            const int gcol = col0 + n * 16 + lr;
            #pragma unroll
            for (int r = 0; r < 4; ++r)
                Cs[(size_t)(grow0 + r) * N + gcol] = acc[m][n][r];
        }
    }
}

// ---------------------------------------------------------------------------
// Big-M MFMA GEMM (for att1): C(M,N)=A@B^T+bias. Tile 64x128x32.
// ---------------------------------------------------------------------------
template<bool ABF16>
__global__ __launch_bounds__(256)
void gemm_mfma(const void* __restrict__ Ap, int lda,
               const unsigned short* __restrict__ Bw, int ldb,
               unsigned short* __restrict__ Cp, int ldc,
               const float* __restrict__ bias,
               int M, int N, int K)
{
    __shared__ __align__(16) unsigned short As[64][40];
    __shared__ __align__(16) unsigned short Bs[128][40];

    const int tid  = threadIdx.x;
    const int lane = tid & 63;
    const int wid  = tid >> 6;
    const int wr   = wid >> 1;
    const int wc   = wid & 1;
    const int row0 = blockIdx.y * 64;
    const int col0 = blockIdx.x * 128;

    const int ar = tid >> 2;
    const int as = (tid & 3) * 8;
    const int br = tid >> 1;
    const int bs = (tid & 1) * 16;

    const int lr = lane & 15;
    const int lk = (lane >> 4) * 8;

    f32x4 acc[2][4];
    #pragma unroll
    for (int m = 0; m < 2; ++m)
        #pragma unroll
        for (int n = 0; n < 4; ++n)
            acc[m][n] = (f32x4){0.f, 0.f, 0.f, 0.f};

    for (int k0 = 0; k0 < K; k0 += 32) {
        ushort8_t aval = {0,0,0,0,0,0,0,0};
        if (row0 + ar < M) {
            if (ABF16) {
                const unsigned short* A16 = (const unsigned short*)Ap;
                aval = *(const ushort8_t*)(A16 + (size_t)(row0 + ar) * lda + k0 + as);
            } else {
                const float* Af = (const float*)Ap;
                const float* p = Af + (size_t)(row0 + ar) * lda + k0 + as;
                float4 v0 = *(const float4*)(p);
                float4 v1 = *(const float4*)(p + 4);
                aval[0] = f2b(v0.x); aval[1] = f2b(v0.y);
                aval[2] = f2b(v0.z); aval[3] = f2b(v0.w);
                aval[4] = f2b(v1.x); aval[5] = f2b(v1.y);
                aval[6] = f2b(v1.z); aval[7] = f2b(v1.w);
            }
        }
        ushort8_t bv0 = {0,0,0,0,0,0,0,0}, bv1 = {0,0,0,0,0,0,0,0};
        if (col0 + br < N) {
            const unsigned short* p = Bw + (size_t)(col0 + br) * ldb + k0 + bs;
            bv0 = *(const ushort8_t*)(p);
            bv1 = *(const ushort8_t*)(p + 8);
        }
        __syncthreads();
        *(ushort8_t*)&As[ar][as]     = aval;
        *(ushort8_t*)&Bs[br][bs]     = bv0;
        *(ushort8_t*)&Bs[br][bs + 8] = bv1;
        __syncthreads();

        short8_t af[2], bf[4];
        #pragma unroll
        for (int m = 0; m < 2; ++m)
            af[m] = *(const short8_t*)&As[wr * 32 + m * 16 + lr][lk];
        #pragma unroll
        for (int n = 0; n < 4; ++n)
            bf[n] = *(const short8_t*)&Bs[wc * 64 + n * 16 + lr][lk];
        #pragma unroll
        for (int m = 0; m < 2; ++m)
            #pragma unroll
            for (int n = 0; n < 4; ++n)
                acc[m][n] = __builtin_amdgcn_mfma_f32_16x16x32_bf16(
                    af[m], bf[n], acc[m][n], 0, 0, 0);
    }

    #pragma unroll
    for (int m = 0; m < 2; ++m) {
        const int grow0 = row0 + wr * 32 + m * 16 + (lane >> 4) * 4;
        #pragma unroll
        for (int n = 0; n < 4; ++n) {
            const int gcol = col0 + wc * 64 + n * 16 + lr;
            if (gcol >= N) continue;
            const float bv = bias[gcol];
            #pragma unroll
            for (int r = 0; r < 4; ++r) {
                const int grow = grow0 + r;
                if (grow >= M) continue;
                Cp[(size_t)grow * ldc + gcol] = f2b(acc[m][n][r] + bv);
            }
        }
    }
}

// ---------------------------------------------------------------------------
__global__ __launch_bounds__(256)
void cvt_bf16_kernel(const float* __restrict__ in, unsigned short* __restrict__ out,
                     int n8)
{
    const int idx = blockIdx.x * 256 + threadIdx.x;
    if (idx >= n8) return;
    const size_t base = (size_t)idx * 8;
    float4 v0 = *(const float4*)(in + base);
    float4 v1 = *(const float4*)(in + base + 4);
    ushort8_t u;
    u[0]=f2b(v0.x); u[1]=f2b(v0.y); u[2]=f2b(v0.z); u[3]=f2b(v0.w);
    u[4]=f2b(v1.x); u[5]=f2b(v1.y); u[6]=f2b(v1.z); u[7]=f2b(v1.w);
    *(ushort8_t*)(out + base) = u;
}

// wcat (8192 x 4480) k-order: [W_hh (2048) | W_ih (2348) | pad (84)]
__global__ __launch_bounds__(256)
void build_wcat_kernel(const float* __restrict__ W_ih, const float* __restrict__ W_hh,
                       unsigned short* __restrict__ wcat)
{
    const int row = blockIdx.x;
    for (int s = threadIdx.x; s < KPAD_ / 8; s += 256) {
        const int k0 = s * 8;
        ushort8_t u;
        if (k0 + 8 <= H_) {
            const float* p = W_hh + (size_t)row * H_ + k0;
            float4 v0 = *(const float4*)(p);
            float4 v1 = *(const float4*)(p + 4);
            u[0]=f2b(v0.x); u[1]=f2b(v0.y); u[2]=f2b(v0.z); u[3]=f2b(v0.w);
            u[4]=f2b(v1.x); u[5]=f2b(v1.y); u[6]=f2b(v1.z); u[7]=f2b(v1.w);
        } else if (k0 >= H_ && k0 + 8 <= KREAL_) {
            const float* p = W_ih + (size_t)row * (EMB_ + E_) + (k0 - H_);
            float4 v0 = *(const float4*)(p);
            float4 v1 = *(const float4*)(p + 4);
            u[0]=f2b(v0.x); u[1]=f2b(v0.y); u[2]=f2b(v0.z); u[3]=f2b(v0.w);
            u[4]=f2b(v1.x); u[5]=f2b(v1.y); u[6]=f2b(v1.z); u[7]=f2b(v1.w);
        } else {
            #pragma unroll
            for (int i = 0; i < 8; ++i) {
                const int k = k0 + i;
                float v = 0.f;
                if (k < KREAL_ && k >= H_) v = W_ih[(size_t)row * (EMB_ + E_) + (k - H_)];
                u[i] = f2b(v);
            }
        }
        *(ushort8_t*)(wcat + (size_t)row * KPAD_ + k0) = u;
    }
}

// wstep (2880 x 2048) rows: [dec_attW (512) | fbeta_W (2048) | fc_W (261) | 0 (59)]
__global__ __launch_bounds__(256)
void build_wstep_kernel(const float* __restrict__ dec_attW,
                        const float* __restrict__ fbeta_W,
                        const float* __restrict__ fc_W,
                        unsigned short* __restrict__ wstep)
{
    const int row = blockIdx.x;
    const int c0  = threadIdx.x * 8;
    const float* src;
    if (row < A_)                 src = dec_attW + (size_t)row * H_ + c0;
    else if (row < A_ + E_)       src = fbeta_W + (size_t)(row - A_) * H_ + c0;
    else if (row < A_ + E_ + VOUT_) src = fc_W + (size_t)(row - A_ - E_) * H_ + c0;
    else                          src = nullptr;
    ushort8_t u = {0,0,0,0,0,0,0,0};
    if (src) {
        float4 v0 = *(const float4*)(src);
        float4 v1 = *(const float4*)(src + 4);
        u[0]=f2b(v0.x); u[1]=f2b(v0.y); u[2]=f2b(v0.z); u[3]=f2b(v0.w);
        u[4]=f2b(v1.x); u[5]=f2b(v1.y); u[6]=f2b(v1.z); u[7]=f2b(v1.w);
    }
    *(ushort8_t*)(wstep + (size_t)row * H_ + c0) = u;
}

// ---------------------------------------------------------------------------
// reduce combined step GEMM partials (8 splits, 256 x 2880) and scatter:
// [0,512) -> att2 ; [512,2560) -> gatelin ; [2560,2821) -> out_y[t-1] (if t>0)
// ---------------------------------------------------------------------------
__global__ __launch_bounds__(256)
void reduce_step(const float* __restrict__ parts, float* __restrict__ att2,
                 float* __restrict__ gatelin, float* __restrict__ outy,
                 const float* __restrict__ dec_attb, const float* __restrict__ fbeta_b,
                 const float* __restrict__ fc_b, int t)
{
    const int i = blockIdx.x * 256 + threadIdx.x;   // over 256*2880
    const int row = i / NSTEP_;
    const int col = i - row * NSTEP_;
    float acc = 0.f;
    #pragma unroll
    for (int s = 0; s < 8; ++s)
        acc += parts[(size_t)s * 256 * NSTEP_ + i];
    if (col < A_) {
        att2[row * A_ + col] = acc + dec_attb[col];
    } else if (col < A_ + E_) {
        const int c = col - A_;
        gatelin[(size_t)row * E_ + c] = acc + fbeta_b[c];
    } else {
        const int c = col - (A_ + E_);
        if (c < VOUT_ && t > 0)
            outy[(size_t)row * T_ * VOUT_ + (size_t)(t - 1) * VOUT_ + c] = acc + fc_b[c];
    }
}

// h0 partial reduce (8 splits, 256 x 2048) -> bf16 into xcat h region
__global__ __launch_bounds__(256)
void reduce_h0(const float* __restrict__ parts, const float* __restrict__ bias,
               unsigned short* __restrict__ xcat)
{
    const int i = blockIdx.x * 256 + threadIdx.x;   // 256*2048
    const int row = i >> 11, col = i & (H_ - 1);
    float acc = bias[col];
    #pragma unroll
    for (int s = 0; s < 8; ++s)
        acc += parts[(size_t)s * 256 * H_ + i];
    xcat[(size_t)row * KPAD_ + col] = f2b(acc);
}

// ---------------------------------------------------------------------------
// e[b,p] = sum_a relu(att1_bf16[b,p,a] + att2[b,a]) * fw[a] + fb
// ---------------------------------------------------------------------------
__global__ __launch_bounds__(256)
void e_kernel(const unsigned short* __restrict__ att1, const float* __restrict__ att2,
              const float* __restrict__ fw, const float* __restrict__ fb,
              float* __restrict__ e)
{
    const int wid  = threadIdx.x >> 6;
    const int lane = threadIdx.x & 63;
    const int row  = blockIdx.x * 4 + wid;
    const int b    = row / P_;
    const unsigned short* a1 = att1 + (size_t)row * A_;
    const float* a2 = att2 + (size_t)b * A_;
    float acc = 0.f;
    #pragma unroll
    for (int a = lane; a < A_; a += 64) {
        float v = b2f(a1[a]) + a2[a];
        v = v > 0.f ? v : 0.f;
        acc = fmaf(v, fw[a], acc);
    }
    #pragma unroll
    for (int off = 32; off > 0; off >>= 1)
        acc += __shfl_down(acc, off);
    if (lane == 0) e[row] = acc + fb[0];
}

// ---------------------------------------------------------------------------
__global__ __launch_bounds__(256)
void softmax_kernel(const float* __restrict__ e, float* __restrict__ alpha,
                    float* __restrict__ out_alpha, int t)
{
    const int b   = blockIdx.x;
    const int tid = threadIdx.x;
    const int wid = tid >> 6, lane = tid & 63;
    __shared__ float red[4];

    float v = (tid < P_) ? e[b * P_ + tid] : -1e30f;

    float m = v;
    #pragma unroll
    for (int off = 32; off > 0; off >>= 1)
        m = fmaxf(m, __shfl_xor(m, off));
    if (lane == 0) red[wid] = m;
    __syncthreads();
    m = fmaxf(fmaxf(red[0], red[1]), fmaxf(red[2], red[3]));
    __syncthreads();

    float p = (tid < P_) ? expf(v - m) : 0.f;
    float s = p;
    #pragma unroll
    for (int off = 32; off > 0; off >>= 1)
        s += __shfl_xor(s, off);
    if (lane == 0) red[wid] = s;
    __syncthreads();
    s = red[0] + red[1] + red[2] + red[3];

    if (tid < P_) {
        const float a = p / s;
        alpha[b * P_ + tid] = a;
        out_alpha[((size_t)b * T_ + t) * P_ + tid] = a;
    }
}

// ---------------------------------------------------------------------------
// xcat[b, AWEOFF_+ei] = bf16( sigmoid(gatelin[b,ei]) * sum_p alpha[b,p]*enc[b,p,ei] )
// ---------------------------------------------------------------------------
__global__ __launch_bounds__(256)
void awe_kernel(const float* __restrict__ alpha,
                const float* __restrict__ encf, const unsigned short* __restrict__ enc16,
                int use16,
                const float* __restrict__ gatelin, unsigned short* __restrict__ xcat)
{
    const int b  = blockIdx.y;
    const int ei = blockIdx.x * 256 + threadIdx.x;
    __shared__ float al[P_];
    if (threadIdx.x < P_) al[threadIdx.x] = alpha[b * P_ + threadIdx.x];
    __syncthreads();

    float acc = 0.f;
    if (use16) {
        const unsigned short* ep = enc16 + (size_t)b * P_ * E_ + ei;
        #pragma unroll 4
        for (int p = 0; p < P_; ++p)
            acc = fmaf(al[p], b2f(ep[(size_t)p * E_]), acc);
    } else {
        const float* ep = encf + (size_t)b * P_ * E_ + ei;
        #pragma unroll 4
        for (int p = 0; p < P_; ++p)
            acc = fmaf(al[p], ep[(size_t)p * E_], acc);
    }

    const float g  = gatelin[(size_t)b * E_ + ei];
    const float sg = 1.f / (1.f + expf(-g));
    xcat[(size_t)b * KPAD_ + AWEOFF_ + ei] = f2b(sg * acc);
}

// ---------------------------------------------------------------------------
// LSTM cell from gates partials (2 K-splits, each 256x8192) + bias; writes
// c (fp32) and h (bf16 into xcat h region).
// ---------------------------------------------------------------------------
__global__ __launch_bounds__(256)
void lstm_kernel(const float* __restrict__ parts, const float* __restrict__ bias4h,
                 float* __restrict__ c, unsigned short* __restrict__ xcat)
{
    const int idx = blockIdx.x * 256 + threadIdx.x;  // b*H + j
    const int b = idx >> 11;
    const int j = idx & (H_ - 1);
    const float* p0 = parts + (size_t)b * 4 * H_;
    const float* p1 = p0 + (size_t)256 * 4 * H_;
    const float gi = bias4h[j]          + p0[j]          + p1[j];
    const float gf = bias4h[H_ + j]     + p0[H_ + j]     + p1[H_ + j];
    const float gg = bias4h[2 * H_ + j] + p0[2 * H_ + j] + p1[2 * H_ + j];
    const float go = bias4h[3 * H_ + j] + p0[3 * H_ + j] + p1[3 * H_ + j];
    const float si = 1.f / (1.f + expf(-gi));
    const float sf = 1.f / (1.f + expf(-gf));
    const float so = 1.f / (1.f + expf(-go));
    const float cn = sf * c[idx] + si * tanhf(gg);
    c[idx] = cn;
    xcat[(size_t)b * KPAD_ + j] = f2b(so * tanhf(cn));
}

// ---------------------------------------------------------------------------
__global__ __launch_bounds__(256)
void gather_kernel(const int* __restrict__ ann, const float* __restrict__ embW,
                   unsigned short* __restrict__ xcat, int t)
{
    const int b = blockIdx.x;
    const int r = ann[b * T_ + t];
    for (int j = threadIdx.x; j < EMB_; j += 256)
        xcat[(size_t)b * KPAD_ + EMBOFF_ + j] = f2b(embW[(size_t)r * EMB_ + j]);
}

__global__ __launch_bounds__(256)
void addvec_kernel(const float* __restrict__ a, const float* __restrict__ b,
                   float* __restrict__ o, int n)
{
    const int i = blockIdx.x * 256 + threadIdx.x;
    if (i < n) o[i] = a[i] + b[i];
}

// ---------------------------------------------------------------------------
extern "C" void kernel_launch(void* const* d_in, const int* in_sizes, int n_in,
                              void* d_out, int out_size, void* d_ws, size_t ws_size,
                              hipStream_t stream)
{
    const float* enc      = (const float*)d_in[0];   // (B,P,E)
    const float* enc_out  = (const float*)d_in[1];   // (B,E)
    const int*   ann      = (const int*)  d_in[2];   // (B,T)
    const float* emb_W    = (const float*)d_in[4];   // (VIN,EMB)
    const float* feat_W   = (const float*)d_in[5];   // (H,E)
    const float* feat_b   = (const float*)d_in[6];
    const float* W_ih     = (const float*)d_in[7];   // (4H, EMB+E)
    const float* W_hh     = (const float*)d_in[8];   // (4H, H)
    const float* b_ih     = (const float*)d_in[9];
    const float* b_hh     = (const float*)d_in[10];
    const float* enc_attW = (const float*)d_in[11];  // (A,E)
    const float* enc_attb = (const float*)d_in[12];
    const float* dec_attW = (const float*)d_in[13];  // (A,H)
    const float* dec_attb = (const float*)d_in[14];
    const float* full_attW= (const float*)d_in[15];  // (1,A)
    const float* full_attb= (const float*)d_in[16];
    const float* fbeta_W  = (const float*)d_in[17];  // (E,H)
    const float* fbeta_b  = (const float*)d_in[18];
    const float* fc_W     = (const float*)d_in[19];  // (VOUT,H)
    const float* fc_b     = (const float*)d_in[20];
    (void)in_sizes; (void)n_in; (void)out_size;

    float* out   = (float*)d_out;
    float* out_y = out;                                 // (B,T,VOUT)
    float* out_a = out + (size_t)B_ * T_ * VOUT_;       // (B,T,P)

    // ---- workspace layout
    char* base = (char*)d_ws;
    size_t off = 0;
    auto alloc = [&](size_t bytes) -> char* {
        char* p = base + off;
        off += (bytes + 255) & ~(size_t)255;
        return p;
    };
    unsigned short* att1_16   = (unsigned short*)alloc((size_t)B_ * P_ * A_ * 2);      // 51.4 MB
    unsigned short* wcat16    = (unsigned short*)alloc((size_t)4 * H_ * KPAD_ * 2);    // 73.4 MB
    unsigned short* wstep16   = (unsigned short*)alloc((size_t)NSTEP_ * H_ * 2);       // 11.8 MB
    unsigned short* encattW16 = (unsigned short*)alloc((size_t)A_ * E_ * 2);
    unsigned short* featW16   = (unsigned short*)alloc((size_t)H_ * E_ * 2);
    unsigned short* encout16  = (unsigned short*)alloc((size_t)B_ * E_ * 2);
    unsigned short* xcat16    = (unsigned short*)alloc((size_t)B_ * KPAD_ * 2);        // 2.3 MB
    float* cbuf    = (float*)alloc((size_t)B_ * H_ * 4);
    float* att2buf = (float*)alloc((size_t)B_ * A_ * 4);
    float* ebuf    = (float*)alloc((size_t)B_ * P_ * 4);
    float* alpha   = (float*)alloc((size_t)B_ * P_ * 4);
    float* gatelin = (float*)alloc((size_t)B_ * E_ * 4);
    float* bias4h  = (float*)alloc((size_t)4 * H_ * 4);
    float* parts   = (float*)alloc((size_t)8 * B_ * NSTEP_ * 4);                       // 23.6 MB
    const size_t enc_elems = (size_t)B_ * P_ * E_;
    const int use16 = (off + enc_elems * 2 <= ws_size) ? 1 : 0;
    unsigned short* enc16 = use16 ? (unsigned short*)alloc(enc_elems * 2) : nullptr;

    const dim3 blk(256);

    // ---- setup / conversions
    addvec_kernel<<<dim3((4 * H_ + 255) / 256), blk, 0, stream>>>(b_ih, b_hh, bias4h, 4 * H_);
    cvt_bf16_kernel<<<dim3((A_ * E_ / 8 + 255) / 256), blk, 0, stream>>>(enc_attW, encattW16, A_ * E_ / 8);
    cvt_bf16_kernel<<<dim3((H_ * E_ / 8 + 255) / 256), blk, 0, stream>>>(feat_W, featW16, H_ * E_ / 8);
    cvt_bf16_kernel<<<dim3((B_ * E_ / 8 + 255) / 256), blk, 0, stream>>>(enc_out, encout16, B_ * E_ / 8);
    build_wcat_kernel<<<dim3(4 * H_), blk, 0, stream>>>(W_ih, W_hh, wcat16);
    build_wstep_kernel<<<dim3(NSTEP_), blk, 0, stream>>>(dec_attW, fbeta_W, fc_W, wstep16);
    hipMemsetAsync(xcat16, 0, (size_t)B_ * KPAD_ * 2, stream);
    hipMemsetAsync(cbuf, 0, (size_t)B_ * H_ * 4, stream);
    if (use16)
        cvt_bf16_kernel<<<dim3((int)(enc_elems / 8 + 255) / 256), blk, 0, stream>>>(enc, enc16, (int)(enc_elems / 8));

    // ---- att1 = enc @ enc_att_W^T + b -> bf16 (B*P, A)
    {
        dim3 g((A_ + 127) / 128, (B_ * P_) / 64);
        if (use16)
            gemm_mfma<true><<<g, blk, 0, stream>>>(enc16, E_, encattW16, E_,
                att1_16, A_, enc_attb, B_ * P_, A_, E_);
        else
            gemm_mfma<false><<<g, blk, 0, stream>>>(enc, E_, encattW16, E_,
                att1_16, A_, enc_attb, B_ * P_, A_, E_);
    }
    // ---- h0 = enc_out @ feat_W^T + b -> bf16 into xcat h region
    gemm_skinny<<<dim3(H_ / 64, 8), blk, 0, stream>>>(encout16, E_, featW16, E_,
                                                      parts, H_, E_ / 8);
    reduce_h0<<<dim3(B_ * H_ / 256), blk, 0, stream>>>(parts, feat_b, xcat16);

    // ---- decode steps; combined GEMM t produces att2/gatelin for step t and
    //      yhat for step t-1 (fc rides one step late).
    for (int t = 0; t <= T_; ++t) {
        gemm_skinny<<<dim3(NSTEP_ / 64, 8), blk, 0, stream>>>(xcat16, KPAD_, wstep16, H_,
                                                              parts, NSTEP_, H_ / 8);
        reduce_step<<<dim3(B_ * NSTEP_ / 256), blk, 0, stream>>>(parts, att2buf, gatelin,
            out_y, dec_attb, fbeta_b, fc_b, t);
        if (t == T_) break;

        e_kernel<<<dim3(B_ * P_ / 4), blk, 0, stream>>>(att1_16, att2buf, full_attW, full_attb, ebuf);
        softmax_kernel<<<dim3(B_), blk, 0, stream>>>(ebuf, alpha, out_a, t);
        awe_kernel<<<dim3(E_ / 256, B_), blk, 0, stream>>>(alpha, enc, enc16, use16,
                                                           gatelin, xcat16);
        gather_kernel<<<dim3(B_), blk, 0, stream>>>(ann, emb_W, xcat16, t);

        // gates partials: xcat @ wcat^T (K=4480 split 2)
        gemm_skinny<<<dim3(4 * H_ / 64, 2), blk, 0, stream>>>(xcat16, KPAD_, wcat16, KPAD_,
                                                              parts, 4 * H_, KPAD_ / 2);
        lstm_kernel<<<dim3(B_ * H_ / 256), blk, 0, stream>>>(parts, bias4h, cbuf, xcat16);
    }
}